// Round 6
// baseline (142.595 us; speedup 1.0000x reference)
//
#include <hip/hip_runtime.h>
#include <hip/hip_bf16.h>

#define NN 256
#define HH 256

typedef __attribute__((ext_vector_type(8))) short short8;
typedef __attribute__((ext_vector_type(4))) short s16x4;
typedef __attribute__((ext_vector_type(4))) float f32x4;

__device__ __forceinline__ ushort f2bf(float x) {
    __hip_bfloat16 h = __float2bfloat16(x);
    return *reinterpret_cast<ushort*>(&h);
}
template <int CTRL>
__device__ __forceinline__ float dpp_add(float x) {
    int y = __builtin_amdgcn_update_dpp(0, __float_as_int(x), CTRL, 0xF, 0xF, true);
    return x + __int_as_float(y);
}
__device__ __forceinline__ float red16(float v) {
    v = dpp_add<0xB1>(v);    // quad_perm(1,0,3,2)
    v = dpp_add<0x4E>(v);    // quad_perm(2,3,0,1)
    v = dpp_add<0x141>(v);   // row_half_mirror
    v = dpp_add<0x140>(v);   // row_mirror
    return v;
}

// Workspace (floats), total 1,423,360 floats = 5,693,440 bytes:
//  P[256][64]@0  Q[256][64]@16384  T[256][256]@32768
//  WA[4][256]@98304  WB[4][256]@99328  WgT bf16[256][64]@100352 (2048 floats)
//  PV[4][4][256][256]@104448  (unnormalized v partials [quarter][z][n][h])
//  ML[4][4][256][2]@1153024   (m,l per [quarter][z][n])
//  VN[256][1024]@1161216      (merged normalized v, [n][z*256+h])
#define WS_P   0
#define WS_Q   16384
#define WS_T   32768
#define WS_WA  98304
#define WS_WB  99328
#define WS_WGT 100352
#define WS_PV  104448
#define WS_ML  1153024
#define WS_VN  1161216

__global__ __launch_bounds__(256) void precompute_kernel(
    const float* __restrict__ ahs, const float* __restrict__ goal,
    const float* __restrict__ action, const float* __restrict__ Wd,
    const float* __restrict__ b_dist, const float* __restrict__ Wg,
    const float* __restrict__ w, const float* __restrict__ a,
    float* __restrict__ ws)
{
    const int b = blockIdx.x;
    const int t = threadIdx.x;
    float* P  = ws + WS_P;
    float* Q  = ws + WS_Q;
    float* T  = ws + WS_T;
    float* WA = ws + WS_WA;
    float* WB = ws + WS_WB;
    ushort* WgT = (ushort*)(ws + WS_WGT);

    if (b < NN) {
        T[b*HH + t] = tanhf(ahs[b*HH + t]);
        if (t < 64) {
            float a0 = action[2*b], a1 = action[2*b+1];
            float g0 = goal[2*b],   g1 = goal[2*b+1];
            P[b*64 + t] = a0*Wd[0*64+t] + a1*Wd[1*64+t]
                        + g0*Wd[2*64+t] + g1*Wd[3*64+t] + b_dist[t];
            Q[b*64 + t] = a0*Wd[4*64+t] + a1*Wd[5*64+t]
                        + g0*Wd[6*64+t] + g1*Wd[7*64+t];
        }
    } else if (b < NN + 16) {
        // WA/WB via wave-cooperative coalesced row dots, one w pass for both
        const int r    = b - NN;
        const int z    = r >> 2;
        const int rg   = r & 3;
        const int wid  = t >> 6;
        const int lane = t & 63;
        const int hbase = rg*64 + wid*16;
        const f32x4 aB = *(const f32x4*)(a + lane*4);
        const f32x4 aA = *(const f32x4*)(a + HH + lane*4);
#pragma unroll 4
        for (int rr = 0; rr < 16; ++rr) {
            const int h = hbase + rr;
            const f32x4 w4 = *(const f32x4*)(w + z*HH*HH + h*HH + lane*4);
            float dA = w4.x*aA.x + w4.y*aA.y + w4.z*aA.z + w4.w*aA.w;
            float dB = w4.x*aB.x + w4.y*aB.y + w4.z*aB.z + w4.w*aB.w;
#pragma unroll
            for (int off = 32; off; off >>= 1) {
                dA += __shfl_xor(dA, off);
                dB += __shfl_xor(dB, off);
            }
            if (lane == 0) { WA[z*HH + h] = dA; WB[z*HH + h] = dB; }
        }
    } else {
        // WgT[h][d] = bf16(Wg[d][h])
#pragma unroll 8
        for (int d = 0; d < 64; ++d) WgT[t*64 + d] = f2bf(Wg[d*HH + t]);
    }
}

// grid 1024: block = (quarter qq, n). j in [qq*64, qq*64+64), 4 chunks of 16.
__global__ __launch_bounds__(256, 4) void gat_partial_kernel(
    const float* __restrict__ ahs, const float* __restrict__ ghs,
    const float* __restrict__ b_gate, float* __restrict__ ws)
{
    const int n    = blockIdx.x & 255;
    const int qq   = blockIdx.x >> 8;
    const int t    = threadIdx.x;
    const int wid  = t >> 6;
    const int lane = t & 63;
    const int quad = lane >> 4;
    const int l15  = lane & 15;
    const int n0   = wid * 64;

    const float* P  = ws + WS_P;
    const float* Q  = ws + WS_Q;
    const float* T  = ws + WS_T;
    const float* WA = ws + WS_WA;
    const float* WB = ws + WS_WB;
    const ushort* WgT = (const ushort*)(ws + WS_WGT);
    float* PV = ws + WS_PV;
    float* ML = ws + WS_ML;

    __shared__ ushort hidb[16][72];
    __shared__ __align__(16) float part[4][16][4];
    __shared__ __align__(16) float alpha_s[16][4];
    __shared__ __align__(16) float scl4[4];
    __shared__ float m_s[4], l_s[4], cz_s[4];
    __shared__ float vred[4][4][260];

    int hcol[4];
#pragma unroll
    for (int nt = 0; nt < 4; ++nt) hcol[nt] = n0 + nt*16 + l15;

    short8 bfrag[4][2];
    float  wa_reg[4][4];
    float  bgv[4];
#pragma unroll
    for (int nt = 0; nt < 4; ++nt) {
#pragma unroll
        for (int kh = 0; kh < 2; ++kh)
            bfrag[nt][kh] = *(const short8*)(WgT + hcol[nt]*64 + kh*32 + quad*8);
#pragma unroll
        for (int z = 0; z < 4; ++z) wa_reg[z][nt] = WA[z*HH + hcol[nt]];
        bgv[nt] = b_gate[hcol[nt]];
    }

    // vacc [z][nt]; k=0 self term carried by quarter 0, quad 0
    float vacc[4][4];
    {
        float av[4];
#pragma unroll
        for (int nt = 0; nt < 4; ++nt) av[nt] = ahs[n*HH + hcol[nt]];
#pragma unroll
        for (int z = 0; z < 4; ++z)
#pragma unroll
            for (int nt = 0; nt < 4; ++nt)
                vacc[z][nt] = (qq == 0 && quad == 0) ? av[nt] : 0.f;
    }

    const int jj_own = t >> 4;        // 0..15
    const int db     = (t & 15) * 4;  // 0..60
    float pn[4];
#pragma unroll
    for (int i = 0; i < 4; ++i) pn[i] = P[n*64 + db + i];

    {
        float pc = 0.f, ps = 0.f;
        for (int h = lane; h < HH; h += 64) {
            float av = ahs[n*HH + h];
            pc = fmaf(av, WB[wid*HH + h], pc);
            ps = fmaf(av, WA[wid*HH + h], ps);
        }
#pragma unroll
        for (int off = 32; off; off >>= 1) {
            pc += __shfl_xor(pc, off);
            ps += __shfl_xor(ps, off);
        }
        if (lane == 0) {
            cz_s[wid] = pc;
            if (qq == 0) {
                float sc = pc + ps;
                float e0 = sc > 0.f ? sc : 0.2f * sc;
                m_s[wid] = e0;
                l_s[wid] = 1.0f;
            } else {
                m_s[wid] = -__builtin_inff();
                l_s[wid] = 0.0f;
            }
        }
    }
    __syncthreads();

    for (int cc = 0; cc < 4; ++cc) {
        const int j0 = qq*64 + cc*16;

        // ---- s1: hid chunk = relu(P[n]+Q[j]) -> bf16 LDS ----
        {
            const int j = j0 + jj_own;
            const float4 qa = *(const float4*)(Q + j*64 + db);
            ushort hv[4];
            hv[0] = f2bf(fmaxf(pn[0] + qa.x, 0.f));
            hv[1] = f2bf(fmaxf(pn[1] + qa.y, 0.f));
            hv[2] = f2bf(fmaxf(pn[2] + qa.z, 0.f));
            hv[3] = f2bf(fmaxf(pn[3] + qa.w, 0.f));
            *(s16x4*)&hidb[jj_own][db] = *(s16x4*)hv;
        }
        __syncthreads();   // B1

        // ---- s2: MFMA U = Hid @ Wg ----
        f32x4 acc[4];
#pragma unroll
        for (int nt = 0; nt < 4; ++nt) acc[nt] = (f32x4){0.f,0.f,0.f,0.f};
        short8 afrag[2];
#pragma unroll
        for (int kh = 0; kh < 2; ++kh)
            afrag[kh] = *(const short8*)&hidb[l15][kh*32 + quad*8];
#pragma unroll
        for (int nt = 0; nt < 4; ++nt) {
            acc[nt] = __builtin_amdgcn_mfma_f32_16x16x32_bf16(
                afrag[0], bfrag[nt][0], acc[nt], 0, 0, 0);
            acc[nt] = __builtin_amdgcn_mfma_f32_16x16x32_bf16(
                afrag[1], bfrag[nt][1], acc[nt], 0, 0, 0);
        }

        // epilogue: vals first (T loads hoistable above the MFMA wait)
        float vals[4][4];   // [nt][r]
#pragma unroll
        for (int r = 0; r < 4; ++r) {
            const int jg = j0 + quad*4 + r;   // D-layout row
            const bool diag = (jg == n);
#pragma unroll
            for (int nt = 0; nt < 4; ++nt) {
                float u = acc[nt][r] + bgv[nt];
                float val;
                if (diag) {
                    val = ghs[n*HH + hcol[nt]];
                } else {
                    float g = 1.0f / (1.0f + __expf(-u));
                    val = g * T[jg*HH + hcol[nt]];
                }
                vals[nt][r] = val;
            }
        }
        // score partials per z (only 4 pp regs live at a time)
#pragma unroll
        for (int z = 0; z < 4; ++z) {
            float pp[4];
#pragma unroll
            for (int r = 0; r < 4; ++r) {
                float s = 0.f;
#pragma unroll
                for (int nt = 0; nt < 4; ++nt)
                    s = fmaf(vals[nt][r], wa_reg[z][nt], s);
                pp[r] = red16(s);
            }
            if (l15 == 0) {
#pragma unroll
                for (int r = 0; r < 4; ++r)
                    part[z][quad*4 + r][wid] = pp[r];
            }
        }
        __syncthreads();   // B2

        // ---- s3: softmax update for head z=wid (lanes 0..15) ----
        {
            const int jj = lane & 15;
            f32x4 pr = *(const f32x4*)&part[wid][jj][0];
            const bool act = lane < 16;
            float s = cz_s[wid] + ((pr.x + pr.y) + (pr.z + pr.w));
            float e = act ? (s > 0.f ? s : 0.2f * s) : -__builtin_inff();
            float mx = e;
#pragma unroll
            for (int off = 8; off; off >>= 1) mx = fmaxf(mx, __shfl_xor(mx, off));
            float m_old = m_s[wid];
            float m_new = fmaxf(m_old, mx);
            float at = act ? __expf(e - m_new) : 0.f;
            float ss = at;
#pragma unroll
            for (int off = 8; off; off >>= 1) ss += __shfl_xor(ss, off);
            if (act) alpha_s[jj][wid] = at;
            if (lane == 0) {
                float scale = __expf(m_old - m_new);
                scl4[wid] = scale;
                l_s[wid]  = l_s[wid] * scale + ss;
                m_s[wid]  = m_new;
            }
        }
        __syncthreads();   // B3

        // ---- s4: vacc update ----
        {
            f32x4 scv = *(const f32x4*)&scl4[0];
#pragma unroll
            for (int nt = 0; nt < 4; ++nt) {
                vacc[0][nt] *= scv.x; vacc[1][nt] *= scv.y;
                vacc[2][nt] *= scv.z; vacc[3][nt] *= scv.w;
            }
#pragma unroll
            for (int r = 0; r < 4; ++r) {
                f32x4 al = *(const f32x4*)&alpha_s[quad*4 + r][0];
#pragma unroll
                for (int nt = 0; nt < 4; ++nt) {
                    float v = vals[nt][r];
                    vacc[0][nt] = fmaf(al.x, v, vacc[0][nt]);
                    vacc[1][nt] = fmaf(al.y, v, vacc[1][nt]);
                    vacc[2][nt] = fmaf(al.z, v, vacc[2][nt]);
                    vacc[3][nt] = fmaf(al.w, v, vacc[3][nt]);
                }
            }
        }
    }

    // quad-reduce via LDS; write unnormalized partials + (m,l)
#pragma unroll
    for (int z = 0; z < 4; ++z)
#pragma unroll
        for (int nt = 0; nt < 4; ++nt)
            vred[quad][z][hcol[nt]] = vacc[z][nt];
    __syncthreads();
#pragma unroll
    for (int z = 0; z < 4; ++z) {
        float s = (vred[0][z][t] + vred[1][z][t]) + (vred[2][z][t] + vred[3][z][t]);
        PV[((qq*4 + z)*NN + n)*HH + t] = s;
    }
    if (lane == 0) {
        ML[((qq*4 + wid)*NN + n)*2 + 0] = m_s[wid];
        ML[((qq*4 + wid)*NN + n)*2 + 1] = l_s[wid];
    }
}

// grid 256 (one per n): merge 4 quarters, normalize -> VN[n][z*256+h]
__global__ __launch_bounds__(256) void gat_merge_kernel(float* __restrict__ ws)
{
    const int n = blockIdx.x;
    const int t = threadIdx.x;
    const float* PV = ws + WS_PV;
    const float* ML = ws + WS_ML;
    float* VN = ws + WS_VN;

    __shared__ float sq[4][4];   // [z][q] = s_q / l*
    if (t < 4) {
        float m[4], l[4];
#pragma unroll
        for (int q = 0; q < 4; ++q) {
            m[q] = ML[((q*4 + t)*NN + n)*2 + 0];
            l[q] = ML[((q*4 + t)*NN + n)*2 + 1];
        }
        float mm = fmaxf(fmaxf(m[0], m[1]), fmaxf(m[2], m[3]));
        float s0 = __expf(m[0]-mm), s1 = __expf(m[1]-mm);
        float s2 = __expf(m[2]-mm), s3 = __expf(m[3]-mm);
        float inv = 1.0f / (l[0]*s0 + l[1]*s1 + l[2]*s2 + l[3]*s3);
        sq[t][0] = s0*inv; sq[t][1] = s1*inv; sq[t][2] = s2*inv; sq[t][3] = s3*inv;
    }
    __syncthreads();
#pragma unroll
    for (int z = 0; z < 4; ++z) {
        float v = 0.f;
#pragma unroll
        for (int q = 0; q < 4; ++q)
            v = fmaf(sq[z][q], PV[((q*4 + z)*NN + n)*HH + t], v);
        VN[n*1024 + z*HH + t] = v;
    }
}

// grid 512: block = (n-tile of 2 rows) x (f-tile of 64), K split across wave pairs.
// V operand is wave-uniform -> scalar loads (s_load); w load coalesced 256B.
__global__ __launch_bounds__(256) void gat_combine_kernel(
    const float* __restrict__ w, const float* __restrict__ bias,
    const float* __restrict__ ws, float* __restrict__ out)
{
    const int n0  = (blockIdx.x >> 2) * 2;
    const int f0  = (blockIdx.x & 3) * 64;
    const int t   = threadIdx.x;
    const int wid = t >> 6;
    const int lane= t & 63;
    const int ni  = wid & 1;
    const int ko  = wid >> 1;
    const float* VN = ws + WS_VN;

    __shared__ float accL[2][64];

    const int row = __builtin_amdgcn_readfirstlane(n0 + ni);
    const float* vrow = VN + row*1024 + ko*512;
    const float* wp   = w + (ko*512)*HH + f0 + lane;

    float a0=0.f, a1=0.f, a2=0.f, a3=0.f;
#pragma unroll 8
    for (int k = 0; k < 512; k += 4) {
        a0 = fmaf(vrow[k+0], wp[(size_t)(k+0)*HH], a0);
        a1 = fmaf(vrow[k+1], wp[(size_t)(k+1)*HH], a1);
        a2 = fmaf(vrow[k+2], wp[(size_t)(k+2)*HH], a2);
        a3 = fmaf(vrow[k+3], wp[(size_t)(k+3)*HH], a3);
    }
    float acc = (a0+a1)+(a2+a3);
    if (ko == 1) accL[ni][lane] = acc;
    __syncthreads();
    if (ko == 0) {
        float tot = acc + accL[ni][lane];
        out[(n0+ni)*HH + f0 + lane] = fmaxf(0.25f*tot, 0.f) + bias[f0+lane];
    }
}

extern "C" void kernel_launch(void* const* d_in, const int* in_sizes, int n_in,
                              void* d_out, int out_size, void* d_ws, size_t ws_size,
                              hipStream_t stream)
{
    const float* ahs    = (const float*)d_in[0];
    const float* ghs    = (const float*)d_in[1];
    const float* goal   = (const float*)d_in[2];
    const float* action = (const float*)d_in[3];
    const float* Wd     = (const float*)d_in[4];
    const float* b_dist = (const float*)d_in[5];
    const float* Wg     = (const float*)d_in[6];
    const float* b_gate = (const float*)d_in[7];
    const float* w      = (const float*)d_in[8];
    const float* a      = (const float*)d_in[9];
    const float* bias   = (const float*)d_in[10];
    float* ws   = (float*)d_ws;     // needs 5,693,440 bytes
    float* outp = (float*)d_out;

    precompute_kernel<<<273, 256, 0, stream>>>(ahs, goal, action, Wd, b_dist, Wg, w, a, ws);
    gat_partial_kernel<<<1024, 256, 0, stream>>>(ahs, ghs, b_gate, ws);
    gat_merge_kernel<<<256, 256, 0, stream>>>(ws);
    gat_combine_kernel<<<512, 256, 0, stream>>>(w, bias, ws, outp);
}